// Round 15
// baseline (153.112 us; speedup 1.0000x reference)
//
#include <hip/hip_runtime.h>
#include <hip/hip_bf16.h>

// Spectral attention: B=2, N=50000, D=256, H=8, Dh=32, K_EIG=32, NUM_BANDS=3
// Key identity: Qf = E^T (x Wq^T + bq) = (E^T x) Wq^T + s * bq, s[k] = sum_n E[n,k]
// N-sized work: U = E^T x (read x once) and out = E @ out_freq (write out once).
// Lessons: r2 arrays spill; r3 no redundant HBM reads; r8 never set
// launch_bounds min-waves; r9 LDS b128 ~12cy is a shared per-CU pipe ->
// don't round-trip the BIG stream (x) through LDS; r10 E is cache-resident;
// r13 E/x share the vmcnt FIFO -> one chokepoint per tile, E via LDS (lgkm);
// r14 expand: 4-wave blocks at 3.05 blocks/CU quantize badly -> more blocks.
// r15: x direct global->reg (double-buffered sets), only E through LDS.

constexpr int D = 256;   // d_model

// ---------------------------------------------------------------- k_colsum
__global__ __launch_bounds__(256) void k_colsum(const float* __restrict__ E,
                                                float* __restrict__ pS, int N) {
  int k = threadIdx.x & 31;
  int rg = threadIdx.x >> 5;
  int rs = (N + 255) >> 8;
  int n0 = blockIdx.x * rs;
  int n1 = n0 + rs; if (n1 > N) n1 = N;
  float acc = 0.f;
  for (int n = n0 + rg; n < n1; n += 8) acc += E[(size_t)n * 32 + k];
  __shared__ float red[256];
  red[threadIdx.x] = acc;
  __syncthreads();
  if (threadIdx.x < 32) {
    float t = red[threadIdx.x];
#pragma unroll
    for (int i = 1; i < 8; ++i) t += red[i * 32 + threadIdx.x];
    pS[blockIdx.x * 32 + threadIdx.x] = t;
  }
}

// ---------------------------------------------------------------- k_partial
// grid = B*nchunk, 512 thr = 8 waves: dh = w&1 (d-half), rp = w>>1 (rows mod 4
// -> disjoint x). Lane owns d-pair. 32 float2 accs. x: global->named regs,
// double-buffered tile sets (pa/pb), NEVER through LDS. E: 32-row tile (4 KB)
// reg->LDS double-buffered; ONE barrier + ONE vmcnt chokepoint per tile.
// 4-way rp reduce in LDS -> pU[bc][32][256].
__global__ __launch_bounds__(512) void k_partial(const float* __restrict__ x,
                                                 const float* __restrict__ E,
                                                 float* __restrict__ pU,
                                                 int N, int nchunk, int rpc) {
  int bc = blockIdx.x;                     // b*nchunk + c
  int c = bc % nchunk;
  int b = bc / nchunk;
  int t = threadIdx.x;
  int w = t >> 6;
  int dh = w & 1;                          // d-half
  int rp = w >> 1;                         // row phase 0..3
  int lane = t & 63;
  int n0 = c * rpc;
  int n1 = n0 + rpc; if (n1 > N) n1 = N;
  int nrows = n1 - n0; if (nrows < 0) nrows = 0;

  __shared__ __align__(16) float4 es[2][256];      //  8 KB E double buffer
  __shared__ float2 rbuf[3][2][8][64];             // 24 KB octet reduce

  float2 a0={0,0},a1={0,0},a2={0,0},a3={0,0},a4={0,0},a5={0,0},a6={0,0},a7={0,0};
  float2 a8={0,0},a9={0,0},a10={0,0},a11={0,0},a12={0,0},a13={0,0},a14={0,0},a15={0,0};
  float2 a16={0,0},a17={0,0},a18={0,0},a19={0,0},a20={0,0},a21={0,0},a22={0,0},a23={0,0};
  float2 a24={0,0},a25={0,0},a26={0,0},a27={0,0},a28={0,0},a29={0,0},a30={0,0},a31={0,0};

  if (nrows > 0) {
    const float* xb = x + (size_t)b * N * D + dh * 128 + 2 * lane;
    const float4* e4 = reinterpret_cast<const float4*>(E);
    int er = t >> 3, eq = t & 7;           // E staging (t<256): row, f4-in-row
    int ntiles = (nrows + 31) >> 5;

#define CLR(r) ((r) < N - 1 ? (r) : (N - 1))
#define XL(tb, off) (*reinterpret_cast<const float2*>( \
    xb + (size_t)CLR((tb) + rp + (off)) * D))

    float2 pa0, pa1, pa2, pa3, pa4, pa5, pa6, pa7;
    float2 pb0={0,0}, pb1={0,0}, pb2={0,0}, pb3={0,0};
    float2 pb4={0,0}, pb5={0,0}, pb6={0,0}, pb7={0,0};
    float4 rea = {0,0,0,0}, reb = {0,0,0,0};

    pa0 = XL(n0, 0);  pa1 = XL(n0, 4);  pa2 = XL(n0, 8);  pa3 = XL(n0, 12);
    pa4 = XL(n0, 16); pa5 = XL(n0, 20); pa6 = XL(n0, 24); pa7 = XL(n0, 28);
    if (t < 256) rea = e4[(size_t)CLR(n0 + er) * 8 + eq];

#define FK(s, A) { A.x = fmaf(s, xq.x, A.x); A.y = fmaf(s, xq.y, A.y); }
#define FMAROW(ep, q) { float2 xq = q; float4 e_;                        \
    e_ = (ep)[0]; FK(e_.x, a0)  FK(e_.y, a1)  FK(e_.z, a2)  FK(e_.w, a3) \
    e_ = (ep)[1]; FK(e_.x, a4)  FK(e_.y, a5)  FK(e_.z, a6)  FK(e_.w, a7) \
    e_ = (ep)[2]; FK(e_.x, a8)  FK(e_.y, a9)  FK(e_.z, a10) FK(e_.w, a11)\
    e_ = (ep)[3]; FK(e_.x, a12) FK(e_.y, a13) FK(e_.z, a14) FK(e_.w, a15)\
    e_ = (ep)[4]; FK(e_.x, a16) FK(e_.y, a17) FK(e_.z, a18) FK(e_.w, a19)\
    e_ = (ep)[5]; FK(e_.x, a20) FK(e_.y, a21) FK(e_.z, a22) FK(e_.w, a23)\
    e_ = (ep)[6]; FK(e_.x, a24) FK(e_.y, a25) FK(e_.z, a26) FK(e_.w, a27)\
    e_ = (ep)[7]; FK(e_.x, a28) FK(e_.y, a29) FK(e_.z, a30) FK(e_.w, a31) }

#define SLOT(buf, j, q, tr) \
    if (rp + 4 * (j) < (tr)) { FMAROW(&es[buf][(rp + 4 * (j)) * 8], q) }

#define TILEBODY(tt, PC, RC, PN, RN) {                                   \
    int buf = (tt) & 1;                                                  \
    if (t < 256) es[buf][t] = RC;  /* vmcnt chokepoint (waits RC) */     \
    __syncthreads();                                                     \
    if ((tt) + 1 < ntiles) {       /* issue next tile's loads */         \
      int tbn = n0 + (((tt) + 1) << 5);                                  \
      PN##0 = XL(tbn, 0);  PN##1 = XL(tbn, 4);                           \
      PN##2 = XL(tbn, 8);  PN##3 = XL(tbn, 12);                          \
      PN##4 = XL(tbn, 16); PN##5 = XL(tbn, 20);                          \
      PN##6 = XL(tbn, 24); PN##7 = XL(tbn, 28);                          \
      if (t < 256) RN = e4[(size_t)CLR(tbn + er) * 8 + eq];              \
    }                                                                    \
    int tr = nrows - ((tt) << 5); if (tr > 32) tr = 32;                  \
    SLOT(buf, 0, PC##0, tr) SLOT(buf, 1, PC##1, tr)                      \
    SLOT(buf, 2, PC##2, tr) SLOT(buf, 3, PC##3, tr)                      \
    SLOT(buf, 4, PC##4, tr) SLOT(buf, 5, PC##5, tr)                      \
    SLOT(buf, 6, PC##6, tr) SLOT(buf, 7, PC##7, tr)                      \
  }

    int tt = 0;
#pragma unroll 1
    for (; tt + 2 <= ntiles; tt += 2) {
      TILEBODY(tt,     pa, rea, pb, reb)
      TILEBODY(tt + 1, pb, reb, pa, rea)
    }
    if (tt < ntiles) TILEBODY(tt, pa, rea, pb, reb)
#undef TILEBODY
#undef SLOT
#undef FMAROW
#undef FK
#undef XL
#undef CLR
  }

  // 4-way rp reduce, octet at a time: rp>0 write (disjoint), rp==0 sums+stores
  float* o = pU + (size_t)bc * 8192 + dh * 128 + 2 * lane;

#define ROCT(g, A0, A1, A2, A3, A4, A5, A6, A7)                          \
  __syncthreads();                                                       \
  if (rp > 0) {                                                          \
    rbuf[rp-1][dh][0][lane] = A0; rbuf[rp-1][dh][1][lane] = A1;          \
    rbuf[rp-1][dh][2][lane] = A2; rbuf[rp-1][dh][3][lane] = A3;          \
    rbuf[rp-1][dh][4][lane] = A4; rbuf[rp-1][dh][5][lane] = A5;          \
    rbuf[rp-1][dh][6][lane] = A6; rbuf[rp-1][dh][7][lane] = A7;          \
  }                                                                      \
  __syncthreads();                                                       \
  if (rp == 0) {                                                         \
    float2 s0, s1, s2, sv;                                               \
    s0 = rbuf[0][dh][0][lane]; s1 = rbuf[1][dh][0][lane]; s2 = rbuf[2][dh][0][lane]; \
    sv.x = (A0.x + s0.x) + (s1.x + s2.x); sv.y = (A0.y + s0.y) + (s1.y + s2.y);      \
    *reinterpret_cast<float2*>(o + ((g) * 8 + 0) * 256) = sv;            \
    s0 = rbuf[0][dh][1][lane]; s1 = rbuf[1][dh][1][lane]; s2 = rbuf[2][dh][1][lane]; \
    sv.x = (A1.x + s0.x) + (s1.x + s2.x); sv.y = (A1.y + s0.y) + (s1.y + s2.y);      \
    *reinterpret_cast<float2*>(o + ((g) * 8 + 1) * 256) = sv;            \
    s0 = rbuf[0][dh][2][lane]; s1 = rbuf[1][dh][2][lane]; s2 = rbuf[2][dh][2][lane]; \
    sv.x = (A2.x + s0.x) + (s1.x + s2.x); sv.y = (A2.y + s0.y) + (s1.y + s2.y);      \
    *reinterpret_cast<float2*>(o + ((g) * 8 + 2) * 256) = sv;            \
    s0 = rbuf[0][dh][3][lane]; s1 = rbuf[1][dh][3][lane]; s2 = rbuf[2][dh][3][lane]; \
    sv.x = (A3.x + s0.x) + (s1.x + s2.x); sv.y = (A3.y + s0.y) + (s1.y + s2.y);      \
    *reinterpret_cast<float2*>(o + ((g) * 8 + 3) * 256) = sv;            \
    s0 = rbuf[0][dh][4][lane]; s1 = rbuf[1][dh][4][lane]; s2 = rbuf[2][dh][4][lane]; \
    sv.x = (A4.x + s0.x) + (s1.x + s2.x); sv.y = (A4.y + s0.y) + (s1.y + s2.y);      \
    *reinterpret_cast<float2*>(o + ((g) * 8 + 4) * 256) = sv;            \
    s0 = rbuf[0][dh][5][lane]; s1 = rbuf[1][dh][5][lane]; s2 = rbuf[2][dh][5][lane]; \
    sv.x = (A5.x + s0.x) + (s1.x + s2.x); sv.y = (A5.y + s0.y) + (s1.y + s2.y);      \
    *reinterpret_cast<float2*>(o + ((g) * 8 + 5) * 256) = sv;            \
    s0 = rbuf[0][dh][6][lane]; s1 = rbuf[1][dh][6][lane]; s2 = rbuf[2][dh][6][lane]; \
    sv.x = (A6.x + s0.x) + (s1.x + s2.x); sv.y = (A6.y + s0.y) + (s1.y + s2.y);      \
    *reinterpret_cast<float2*>(o + ((g) * 8 + 6) * 256) = sv;            \
    s0 = rbuf[0][dh][7][lane]; s1 = rbuf[1][dh][7][lane]; s2 = rbuf[2][dh][7][lane]; \
    sv.x = (A7.x + s0.x) + (s1.x + s2.x); sv.y = (A7.y + s0.y) + (s1.y + s2.y);      \
    *reinterpret_cast<float2*>(o + ((g) * 8 + 7) * 256) = sv;            \
  }

  ROCT(0, a0,  a1,  a2,  a3,  a4,  a5,  a6,  a7)
  ROCT(1, a8,  a9,  a10, a11, a12, a13, a14, a15)
  ROCT(2, a16, a17, a18, a19, a20, a21, a22, a23)
  ROCT(3, a24, a25, a26, a27, a28, a29, a30, a31)
#undef ROCT
}

// ---------------------------------------------------------------- k_reduce
__global__ __launch_bounds__(256) void k_reduce(const float* __restrict__ pU,
                                                float* __restrict__ U, int nchunk) {
  int e = blockIdx.x * 32 + (threadIdx.x & 31);
  int sub = threadIdx.x >> 5;              // 0..7
  int b = e >> 13;
  int kd = e & 8191;
  const float* p = pU + (size_t)b * nchunk * 8192 + kd;
  float a0 = 0.f, a1 = 0.f, a2 = 0.f, a3 = 0.f;
  float a4 = 0.f, a5 = 0.f, a6 = 0.f, a7 = 0.f;
  int c = sub;
#pragma unroll 1
  for (; c + 56 < nchunk; c += 64) {
    a0 += p[(size_t)c * 8192];
    a1 += p[(size_t)(c + 8) * 8192];
    a2 += p[(size_t)(c + 16) * 8192];
    a3 += p[(size_t)(c + 24) * 8192];
    a4 += p[(size_t)(c + 32) * 8192];
    a5 += p[(size_t)(c + 40) * 8192];
    a6 += p[(size_t)(c + 48) * 8192];
    a7 += p[(size_t)(c + 56) * 8192];
  }
  for (; c < nchunk; c += 8) a0 += p[(size_t)c * 8192];
  __shared__ float red[256];
  red[threadIdx.x] = ((a0 + a1) + (a2 + a3)) + ((a4 + a5) + (a6 + a7));
  __syncthreads();
  if (threadIdx.x < 32) {
    float s = red[threadIdx.x];
#pragma unroll
    for (int i = 1; i < 8; ++i) s += red[i * 32 + threadIdx.x];
    U[e] = s;
  }
}

// ---------------------------------------------------------------- k_project
__global__ __launch_bounds__(256) void k_project(
    const float* __restrict__ U, const float* __restrict__ pS,
    const float* __restrict__ Wq, const float* __restrict__ bq,
    const float* __restrict__ Wk, const float* __restrict__ bk,
    const float* __restrict__ Wv, const float* __restrict__ bv,
    const float* __restrict__ ev, const float* __restrict__ bb,
    const float* __restrict__ fw,
    float* __restrict__ Qfg, float* __restrict__ Kfg, float* __restrict__ Vfg) {
  int blk = blockIdx.x;                    // b*32 + k
  int k = blk & 31;
  int t = threadIdx.x;
  __shared__ __align__(16) float u[256];
  __shared__ float red[256];
  u[t] = U[(size_t)blk * 256 + t];
  red[t] = pS[t * 32 + k];
  __syncthreads();
#pragma unroll
  for (int off = 128; off > 0; off >>= 1) {
    if (t < off) red[t] += red[t + off];
    __syncthreads();
  }
  float sk = red[0];

  // filter response — FP64 to match numpy ref branch semantics
  float mnf = ev[0], mxf = ev[0];
#pragma unroll
  for (int i = 1; i < 32; ++i) { float v = ev[i]; mnf = fminf(mnf, v); mxf = fmaxf(mxf, v); }
  double mn = (double)mnf, mx = (double)mxf;
  double lam = ((double)ev[k] - mn) / (mx - mn + 1e-8);
  int h = t >> 5;
  float g = 0.f;
#pragma unroll
  for (int i = 0; i < 3; ++i) {
    double lo = (double)bb[h * 4 + i], hi = (double)bb[h * 4 + i + 1];
    if (lam >= lo && lam < hi) g = fw[(h * 3 + i) * 32 + k];
  }

  const float4* u4 = reinterpret_cast<const float4*>(u);
  const float4* wq4 = reinterpret_cast<const float4*>(Wq) + (size_t)t * 64;
  const float4* wk4 = reinterpret_cast<const float4*>(Wk) + (size_t)t * 64;
  const float4* wv4 = reinterpret_cast<const float4*>(Wv) + (size_t)t * 64;
  float aq = 0.f, ak = 0.f, av = 0.f;
#pragma unroll 4
  for (int j = 0; j < 64; ++j) {
    float4 uv = u4[j];
    float4 q = wq4[j], kk = wk4[j], vv = wv4[j];
    aq = fmaf(uv.x, q.x, aq);  aq = fmaf(uv.y, q.y, aq);
    aq = fmaf(uv.z, q.z, aq);  aq = fmaf(uv.w, q.w, aq);
    ak = fmaf(uv.x, kk.x, ak); ak = fmaf(uv.y, kk.y, ak);
    ak = fmaf(uv.z, kk.z, ak); ak = fmaf(uv.w, kk.w, ak);
    av = fmaf(uv.x, vv.x, av); av = fmaf(uv.y, vv.y, av);
    av = fmaf(uv.z, vv.z, av); av = fmaf(uv.w, vv.w, av);
  }
  Qfg[(size_t)blk * 256 + t] = (aq + bq[t] * sk) * g;
  Kfg[(size_t)blk * 256 + t] = (ak + bk[t] * sk) * g;
  Vfg[(size_t)blk * 256 + t] = (av + bv[t] * sk) * g;
}

// ---------------------------------------------------------------- k_attn
__global__ __launch_bounds__(1024) void k_attn(const float* __restrict__ Qfg,
                                               const float* __restrict__ Kfg,
                                               const float* __restrict__ Vfg,
                                               float* __restrict__ of) {
  int blk = blockIdx.x;                    // b*8 + h
  int b = blk >> 3, h = blk & 7;
  int tid = threadIdx.x;
  int row = tid >> 5, col = tid & 31;
  __shared__ float Q[32][33], Kt[32][33], V[32][33], A[32][33];
  size_t base = (size_t)b * 32 * 256 + h * 32;
  Q[row][col]  = Qfg[base + row * 256 + col];
  Kt[row][col] = Kfg[base + row * 256 + col];
  V[row][col]  = Vfg[base + row * 256 + col];
  __syncthreads();
  float sc = 0.f;
#pragma unroll
  for (int d0 = 0; d0 < 32; ++d0) sc = fmaf(Q[row][d0], Kt[col][d0], sc);
  sc *= 0.17677669529663687f;              // 1/sqrt(32)
  float m = sc;
#pragma unroll
  for (int o = 16; o > 0; o >>= 1) m = fmaxf(m, __shfl_xor(m, o, 32));
  float p = expf(sc - m);
  float su = p;
#pragma unroll
  for (int o = 16; o > 0; o >>= 1) su += __shfl_xor(su, o, 32);
  A[row][col] = p / su;
  __syncthreads();
  float o_ = 0.f;
#pragma unroll
  for (int l = 0; l < 32; ++l) o_ = fmaf(A[row][l], V[l][col], o_);
  of[base + row * 256 + col] = o_;
}

// ---------------------------------------------------------------- k_expand
// out[b,n,d] = sum_k E[n,k]*of[b,k,d]. rows=32 -> 1563 blocks (6.1/CU, no
// residency quantization). Thread = (bb = t>>7 batch, dp = t&127 d-pair);
// of in 32 float2 regs; E tile 4 KB staged once; float2 stores (512B/instr).
__global__ __launch_bounds__(256) void k_expand(const float* __restrict__ E,
                                                const float* __restrict__ of,
                                                float* __restrict__ out, int N) {
  int n0 = blockIdx.x * 32;
  int n1 = n0 + 32; if (n1 > N) n1 = N;
  int nr = n1 - n0;
  if (nr <= 0) return;
  int t = threadIdx.x;
  int bb = t >> 7;                         // batch
  int dp = t & 127;                        // d-pair

  __shared__ __align__(16) float4 es[256]; // 32 rows x 8 f4 = 4 KB
  {
    const float4* e4 = reinterpret_cast<const float4*>(E);
    int r = n0 + (t >> 3); if (r > N - 1) r = N - 1;
    es[t] = e4[(size_t)r * 8 + (t & 7)];
  }

  const float* ofb = of + (size_t)bb * 8192 + 2 * dp;
  float2 v0  = *(const float2*)(ofb +  0*256), v1  = *(const float2*)(ofb +  1*256);
  float2 v2  = *(const float2*)(ofb +  2*256), v3  = *(const float2*)(ofb +  3*256);
  float2 v4  = *(const float2*)(ofb +  4*256), v5  = *(const float2*)(ofb +  5*256);
  float2 v6  = *(const float2*)(ofb +  6*256), v7  = *(const float2*)(ofb +  7*256);
  float2 v8  = *(const float2*)(ofb +  8*256), v9  = *(const float2*)(ofb +  9*256);
  float2 v10 = *(const float2*)(ofb + 10*256), v11 = *(const float2*)(ofb + 11*256);
  float2 v12 = *(const float2*)(ofb + 12*256), v13 = *(const float2*)(ofb + 13*256);
  float2 v14 = *(const float2*)(ofb + 14*256), v15 = *(const float2*)(ofb + 15*256);
  float2 v16 = *(const float2*)(ofb + 16*256), v17 = *(const float2*)(ofb + 17*256);
  float2 v18 = *(const float2*)(ofb + 18*256), v19 = *(const float2*)(ofb + 19*256);
  float2 v20 = *(const float2*)(ofb + 20*256), v21 = *(const float2*)(ofb + 21*256);
  float2 v22 = *(const float2*)(ofb + 22*256), v23 = *(const float2*)(ofb + 23*256);
  float2 v24 = *(const float2*)(ofb + 24*256), v25 = *(const float2*)(ofb + 25*256);
  float2 v26 = *(const float2*)(ofb + 26*256), v27 = *(const float2*)(ofb + 27*256);
  float2 v28 = *(const float2*)(ofb + 28*256), v29 = *(const float2*)(ofb + 29*256);
  float2 v30 = *(const float2*)(ofb + 30*256), v31 = *(const float2*)(ofb + 31*256);

  __syncthreads();

  float* ob = out + (size_t)bb * N * D + 2 * dp;

#define EX(s, vk, A) { A.x = fmaf(s, vk.x, A.x); A.y = fmaf(s, vk.y, A.y); }
#pragma unroll 2
  for (int r = 0; r < nr; ++r) {
    const float4* ep = &es[r * 8];
    float4 e0 = ep[0], e1 = ep[1], e2 = ep[2], e3 = ep[3];
    float4 e4_ = ep[4], e5 = ep[5], e6 = ep[6], e7 = ep[7];
    float2 oA = {0.f, 0.f}, oB = {0.f, 0.f};
    EX(e0.x, v0,  oA) EX(e0.y, v1,  oB) EX(e0.z, v2,  oA) EX(e0.w, v3,  oB)
    EX(e1.x, v4,  oA) EX(e1.y, v5,  oB) EX(e1.z, v6,  oA) EX(e1.w, v7,  oB)
    EX(e2.x, v8,  oA) EX(e2.y, v9,  oB) EX(e2.z, v10, oA) EX(e2.w, v11, oB)
    EX(e3.x, v12, oA) EX(e3.y, v13, oB) EX(e3.z, v14, oA) EX(e3.w, v15, oB)
    EX(e4_.x, v16, oA) EX(e4_.y, v17, oB) EX(e4_.z, v18, oA) EX(e4_.w, v19, oB)
    EX(e5.x, v20, oA) EX(e5.y, v21, oB) EX(e5.z, v22, oA) EX(e5.w, v23, oB)
    EX(e6.x, v24, oA) EX(e6.y, v25, oB) EX(e6.z, v26, oA) EX(e6.w, v27, oB)
    EX(e7.x, v28, oA) EX(e7.y, v29, oB) EX(e7.z, v30, oA) EX(e7.w, v31, oB)
    float2 o2;
    o2.x = oA.x + oB.x;
    o2.y = oA.y + oB.y;
    *reinterpret_cast<float2*>(ob + (size_t)(n0 + r) * D) = o2;
  }
#undef EX
}

// ---------------------------------------------------------------- launch
extern "C" void kernel_launch(void* const* d_in, const int* in_sizes, int n_in,
                              void* d_out, int out_size, void* d_ws, size_t ws_size,
                              hipStream_t stream) {
  const float* x  = (const float*)d_in[0];
  const float* E  = (const float*)d_in[1];
  const float* ev = (const float*)d_in[2];
  const float* Wq = (const float*)d_in[3];
  const float* bq = (const float*)d_in[4];
  const float* Wk = (const float*)d_in[5];
  const float* bk = (const float*)d_in[6];
  const float* Wv = (const float*)d_in[7];
  const float* bv = (const float*)d_in[8];
  const float* bb = (const float*)d_in[9];
  const float* fw = (const float*)d_in[10];
  float* out = (float*)d_out;
  float* ws  = (float*)d_ws;

  const int N = in_sizes[1] / 32;          // 50000
  const int B = in_sizes[0] / (N * 256);   // 2

  // workspace layout (floats)
  float* U   = ws;                         // B*32*256 = 16384
  float* Qfg = ws + 16384;
  float* Kfg = ws + 32768;
  float* Vfg = ws + 49152;
  float* of  = ws + 65536;
  float* pS  = ws + 81920;                 // 256*32 = 8192
  float* pU  = ws + 90112;                 // B*nchunk*8192 floats

  int nchunk = 512;
  if ((90112 + (size_t)B * nchunk * 8192) * sizeof(float) > ws_size) nchunk = 256;
  int rpc = (N + nchunk - 1) / nchunk;

  k_colsum<<<256, 256, 0, stream>>>(E, pS, N);
  k_partial<<<B * nchunk, 512, 0, stream>>>(x, E, pU, N, nchunk, rpc);
  k_reduce<<<B * 8192 / 32, 256, 0, stream>>>(pU, U, nchunk);
  k_project<<<B * 32, 256, 0, stream>>>(U, pS, Wq, bq, Wk, bk, Wv, bv,
                                        ev, bb, fw, Qfg, Kfg, Vfg);
  k_attn<<<B * 8, 1024, 0, stream>>>(Qfg, Kfg, Vfg, of);
  int nbr = (N + 31) / 32;
  k_expand<<<nbr, 256, 0, stream>>>(E, of, out, N);
}